// Round 18
// baseline (118.778 us; speedup 1.0000x reference)
//
#include <hip/hip_runtime.h>
#include <hip/hip_cooperative_groups.h>
#include <cfloat>

namespace cg = cooperative_groups;

// Problem dims (fixed by reference)
#define BB   256   // batch
#define DIM  512
#define NN   196

typedef __attribute__((ext_vector_type(8))) short bf16x8;   // 8 bf16 (4 VGPRs)
typedef __attribute__((ext_vector_type(4))) float f32x4;    // MFMA acc

__device__ __forceinline__ ushort f2bf(float x) {          // RNE f32->bf16
    unsigned u = __float_as_uint(x);
    return (ushort)((u + 0x7FFFu + ((u >> 16) & 1u)) >> 16);
}

__device__ __forceinline__ bf16x8 pack8(float4 a, float4 b) {
    union { bf16x8 v; ushort u[8]; } r;
    r.u[0] = f2bf(a.x); r.u[1] = f2bf(a.y); r.u[2] = f2bf(a.z); r.u[3] = f2bf(a.w);
    r.u[4] = f2bf(b.x); r.u[5] = f2bf(b.y); r.u[6] = f2bf(b.z); r.u[7] = f2bf(b.w);
    return r.v;
}

// ---------------------------------------------------------------------------
// SINGLE cooperative kernel: phase 1 = fused bf16-convert + MFMA prep
// (16 waves/block: wave wv owns i-subtile s=wv&1, k-chunk c=wv>>1 of 64;
// partials LDS-reduced), grid.sync(), phase 2 = r6-proven read.
// Removes 2 dispatch boundaries + the convert dispatch entirely.
// grid 256 x 1024, LDS peak 48 KB -> 1 block/CU, cooperative-co-resident.
// Fragment maps (m89-verified): A lane l -> row=l&15, k=8*(l>>4)+j ;
// B lane l -> col=l&15, k same ; D lane l -> col=l&15, row=4*(l>>4)+reg.
// ---------------------------------------------------------------------------
__global__ __launch_bounds__(1024) void fused_kernel(
    const float* __restrict__ memory,    // (2,BB,DIM)
    const float* __restrict__ control,   // (2,BB,DIM)
    const float* __restrict__ W_mem,     // (DIM,DIM) [k][i]
    const float* __restrict__ b_mem,     // (DIM)
    const float* __restrict__ W_concat,  // (2*DIM,DIM) [c][j]
    const float* __restrict__ W_attn,    // (DIM,1)
    const float* __restrict__ know,      // (BB,DIM,NN)
    float* __restrict__ w_ws,            // (BB,DIM) scratch
    float* __restrict__ out)             // (BB,NN)
{
    __shared__ __align__(16) unsigned char smem[49152];   // 48 KB union

    const int tid = threadIdx.x;
    const int blk = blockIdx.x;

    // ==================== phase 1: prep tile (b0, i0) ====================
    {
        const int b0 = (blk & 15) * 16;
        const int i0 = (blk >> 4) * 32;
        ushort (*mus)[16][520] = (ushort (*)[16][520])smem;  // 33.3 KB

        const float* mem_in = memory  + (size_t)BB * DIM;   // memory[-1]
        const float* ctl_in = control + (size_t)BB * DIM;   // control[-1]

        // stage m,u for 16 b rows -> bf16 LDS (4096 f4, 4/thread; a uniform/p)
        #pragma unroll
        for (int p = 0; p < 4; ++p) {
            const int idx = p * 1024 + tid;       // 0..4095
            const int a   = idx >> 11;            // 0 = m, 1 = u
            const int rb  = (idx >> 7) & 15;
            const int k4  = idx & 127;
            const float* src = a ? ctl_in : mem_in;
            float4 q = *(const float4*)&src[(size_t)(b0 + rb) * DIM + k4 * 4];
            if (a) {
                const float4 wa = ((const float4*)W_attn)[k4];
                q.x *= wa.x; q.y *= wa.y; q.z *= wa.z; q.w *= wa.w;
            }
            uint2 o;
            o.x = (unsigned)f2bf(q.x) | ((unsigned)f2bf(q.y) << 16);
            o.y = (unsigned)f2bf(q.z) | ((unsigned)f2bf(q.w) << 16);
            *(uint2*)&mus[a][rb][k4 * 4] = o;
        }
        __syncthreads();

        const int wv = tid >> 6;        // 0..15
        const int l  = tid & 63;
        const int s  = wv & 1;          // i-subtile (16 i each)
        const int c  = wv >> 1;         // k-chunk of 64
        const int fr = l & 15;
        const int fk = (l >> 4) * 8;
        const int ib = i0 + s * 16 + fr;

        f32x4 accM = {0.f,0.f,0.f,0.f}, acc1 = {0.f,0.f,0.f,0.f}, acc2 = {0.f,0.f,0.f,0.f};
        const float* wmp = W_mem + ib;
        const float* c1p = W_concat + (size_t)ib * DIM;
        const float* c2p = W_concat + (size_t)(DIM + ib) * DIM;

        #pragma unroll
        for (int ts = 0; ts < 2; ++ts) {
            const int k = c * 64 + ts * 32 + fk;
            const bf16x8 am = *(const bf16x8*)&mus[0][fr][k];
            const bf16x8 au = *(const bf16x8*)&mus[1][fr][k];
            float wmv[8];
            #pragma unroll
            for (int j = 0; j < 8; ++j) wmv[j] = wmp[(size_t)(k + j) * DIM];
            union { bf16x8 v; ushort u[8]; } bm;
            #pragma unroll
            for (int j = 0; j < 8; ++j) bm.u[j] = f2bf(wmv[j]);
            const bf16x8 b1 = pack8(*(const float4*)&c1p[k], *(const float4*)&c1p[k + 4]);
            const bf16x8 b2 = pack8(*(const float4*)&c2p[k], *(const float4*)&c2p[k + 4]);
            accM = __builtin_amdgcn_mfma_f32_16x16x32_bf16(am, bm.v, accM, 0, 0, 0);
            acc1 = __builtin_amdgcn_mfma_f32_16x16x32_bf16(au, b1,   acc1, 0, 0, 0);
            acc2 = __builtin_amdgcn_mfma_f32_16x16x32_bf16(au, b2,   acc2, 0, 0, 0);
        }

        __syncthreads();                 // all waves done with mus -> reuse as P
        float* P = (float*)smem;         // [3][16][256] = 48 KB
        const int rb0 = (l >> 4) * 4;
        #pragma unroll
        for (int r = 0; r < 4; ++r) {
            const int idx = (rb0 + r) * 16 + fr;
            P[           wv * 256 + idx] = accM[r];
            P[4096     + wv * 256 + idx] = acc1[r];
            P[8192     + wv * 256 + idx] = acc2[r];
        }
        __syncthreads();
        if (tid < 512) {
            const int s2 = tid >> 8, idx = tid & 255;
            float sm = 0.f, v1 = 0.f, v2 = 0.f;
            #pragma unroll
            for (int cc = 0; cc < 8; ++cc) {
                const int w2 = cc * 2 + s2;
                sm += P[       w2 * 256 + idx];
                v1 += P[4096 + w2 * 256 + idx];
                v2 += P[8192 + w2 * 256 + idx];
            }
            const int b = b0 + (idx >> 4);
            const int i = i0 + s2 * 16 + (idx & 15);
            w_ws[(size_t)b * DIM + i] = (sm + b_mem[i]) * v1 + v2;
        }
    }

    __threadfence();
    cg::this_grid().sync();

    // ==================== phase 2: read (r6 body, b = blk) ====================
    {
        const int tx = tid & 63;
        const int ty = tid >> 6;
        const int b  = blk;
        float*  w_s     = (float*)smem;                       // 2048 B
        float4* part_lg = (float4*)(smem + 2048);             // 12800 B
        float4* part_ks = (float4*)(smem + 2048 + 12800);     // 12800 B
        float*  tmp     = (float*)(smem + 2048 + 25600);      // 1024 B
        float*  bc      = (float*)(smem + 2048 + 25600 + 1024);

        if (tid < DIM) w_s[tid] = w_ws[(size_t)b * DIM + tid];
        __syncthreads();

        float4 lg = make_float4(0.f, 0.f, 0.f, 0.f);
        float4 ks = make_float4(0.f, 0.f, 0.f, 0.f);
        if (tx < 49) {
            const float4* kp = (const float4*)(know + (size_t)b * DIM * NN)
                             + (size_t)(ty * 32) * 49 + tx;
            const float* wp = w_s + ty * 32;
            #pragma unroll 8
            for (int dd = 0; dd < 32; ++dd) {
                const float4 kv = kp[(size_t)dd * 49];
                const float  wv = wp[dd];
                lg.x = fmaf(kv.x, wv, lg.x); lg.y = fmaf(kv.y, wv, lg.y);
                lg.z = fmaf(kv.z, wv, lg.z); lg.w = fmaf(kv.w, wv, lg.w);
                ks.x += kv.x; ks.y += kv.y; ks.z += kv.z; ks.w += kv.w;
            }
            part_lg[ty * 50 + tx] = lg;
            part_ks[ty * 50 + tx] = ks;
        }
        __syncthreads();

        float lgn = 0.f, ksn = 0.f;
        if (tid < NN) {
            const int ng = tid >> 2, j = tid & 3;
            #pragma unroll
            for (int t = 0; t < 16; ++t) {
                lgn += ((const float*)&part_lg[t * 50 + ng])[j];
                ksn += ((const float*)&part_ks[t * 50 + ng])[j];
            }
        }

        if (tid < 256) tmp[tid] = (tid < NN) ? lgn : -FLT_MAX;
        __syncthreads();
        if (tid < 64) {
            float m = fmaxf(fmaxf(tmp[tid], tmp[tid + 64]),
                            fmaxf(tmp[tid + 128], tmp[tid + 192]));
            #pragma unroll
            for (int o = 32; o; o >>= 1) m = fmaxf(m, __shfl_down(m, o));
            if (tid == 0) bc[0] = m;
        }
        __syncthreads();

        const float e = (tid < NN) ? __expf(lgn - bc[0]) : 0.f;
        if (tid < 256) tmp[tid] = e;
        __syncthreads();
        if (tid < 64) {
            float s = tmp[tid] + tmp[tid + 64] + tmp[tid + 128] + tmp[tid + 192];
            #pragma unroll
            for (int o = 32; o; o >>= 1) s += __shfl_down(s, o);
            if (tid == 0) bc[1] = s;
        }
        __syncthreads();

        if (tid < NN) out[(size_t)b * NN + tid] = e / bc[1] * ksn;
    }
}

// ---------------------------------------------------------------------------
// Fallback path (r11 f32 prep + r6 read) — used only if cooperative launch
// is rejected by the runtime.
// ---------------------------------------------------------------------------
__global__ __launch_bounds__(512, 4) void prep_fallback(
    const float* __restrict__ memory, const float* __restrict__ control,
    const float* __restrict__ W_mem, const float* __restrict__ b_mem,
    const float* __restrict__ W_concat, const float* __restrict__ W_attn,
    float* __restrict__ w_out)
{
    __shared__ float4 MU4[4][DIM];
    __shared__ float  buf[12288];

    const int tid = threadIdx.x;
    const int il  = tid & 31;
    const int kg  = tid >> 5;
    const int b0  = blockIdx.x * 8;
    const int i0  = blockIdx.y * 32;

    const float* mem_in = memory  + (size_t)BB * DIM;
    const float* ctl_in = control + (size_t)BB * DIM;

    {
        const float wa = W_attn[tid];
        #pragma unroll
        for (int p = 0; p < 4; ++p) {
            MU4[p][tid] = make_float4(
                mem_in[(size_t)(b0 + 2 * p)     * DIM + tid],
                ctl_in[(size_t)(b0 + 2 * p)     * DIM + tid] * wa,
                mem_in[(size_t)(b0 + 2 * p + 1) * DIM + tid],
                ctl_in[(size_t)(b0 + 2 * p + 1) * DIM + tid] * wa);
        }
    }

    float am[8] = {}, a1[8] = {}, a2[8] = {};
    const int sr = tid >> 4;
    const int sc = tid & 15;
    float2* WT = (float2*)buf;

    float4 f1 = *(const float4*)&W_concat[(size_t)(i0 + sr) * DIM + sc * 4];
    float4 f2 = *(const float4*)&W_concat[(size_t)(DIM + i0 + sr) * DIM + sc * 4];
    float wmc[4], wmn[4];
    #pragma unroll
    for (int j = 0; j < 4; ++j)
        wmc[j] = W_mem[(size_t)(kg * 4 + j) * DIM + i0 + il];

    for (int kt = 0; kt < DIM; kt += 64) {
        __syncthreads();
        {
            const float* f1f = (const float*)&f1;
            const float* f2f = (const float*)&f2;
            #pragma unroll
            for (int j = 0; j < 4; ++j)
                WT[(sc * 4 + j) * 33 + sr] = make_float2(f1f[j], f2f[j]);
        }
        if (kt + 64 < DIM) {
            f1 = *(const float4*)&W_concat[(size_t)(i0 + sr) * DIM + kt + 64 + sc * 4];
            f2 = *(const float4*)&W_concat[(size_t)(DIM + i0 + sr) * DIM + kt + 64 + sc * 4];
        }
        __syncthreads();
        if (kt + 64 < DIM) {
            #pragma unroll
            for (int j = 0; j < 4; ++j)
                wmn[j] = W_mem[(size_t)(kt + 64 + kg * 4 + j) * DIM + i0 + il];
        }
        #pragma unroll
        for (int j = 0; j < 4; ++j) {
            const int kl = kg * 4 + j;
            const int k  = kt + kl;
            const float2 cc = WT[kl * 33 + il];
            #pragma unroll
            for (int p = 0; p < 4; ++p) {
                const float4 muv = MU4[p][k];
                am[2*p]   = fmaf(muv.x, wmc[j], am[2*p]);
                a1[2*p]   = fmaf(muv.y, cc.x,   a1[2*p]);
                a2[2*p]   = fmaf(muv.y, cc.y,   a2[2*p]);
                am[2*p+1] = fmaf(muv.z, wmc[j], am[2*p+1]);
                a1[2*p+1] = fmaf(muv.w, cc.x,   a1[2*p+1]);
                a2[2*p+1] = fmaf(muv.w, cc.y,   a2[2*p+1]);
            }
        }
        #pragma unroll
        for (int j = 0; j < 4; ++j) wmc[j] = wmn[j];
    }

    __syncthreads();
    #pragma unroll
    for (int b = 0; b < 8; ++b) {
        const int row = (kg * 8 + b) * 32 + il;
        buf[row]        = am[b];
        buf[4096 + row] = a1[b];
        buf[8192 + row] = a2[b];
    }
    __syncthreads();
    if (tid < 256) {
        const int rb = tid >> 5, ri = tid & 31;
        float sm = 0.f, s1 = 0.f, s2 = 0.f;
        #pragma unroll
        for (int t = 0; t < 16; ++t) {
            const int row = (t * 8 + rb) * 32 + ri;
            sm += buf[row];
            s1 += buf[4096 + row];
            s2 += buf[8192 + row];
        }
        w_out[(size_t)(b0 + rb) * DIM + i0 + ri] =
            (sm + b_mem[i0 + ri]) * s1 + s2;
    }
}

__global__ __launch_bounds__(1024) void read_kernel(
    const float* __restrict__ know, const float* __restrict__ w,
    float* __restrict__ out)
{
    __shared__ float  w_s[DIM];
    __shared__ float4 part_lg[16][50];
    __shared__ float4 part_ks[16][50];
    __shared__ float  tmp[256];
    __shared__ float  bc[2];

    const int tx  = threadIdx.x;
    const int ty  = threadIdx.y;
    const int tid = ty * 64 + tx;
    const int b   = blockIdx.x;

    if (tid < DIM) w_s[tid] = w[(size_t)b * DIM + tid];
    __syncthreads();

    float4 lg = make_float4(0.f, 0.f, 0.f, 0.f);
    float4 ks = make_float4(0.f, 0.f, 0.f, 0.f);
    if (tx < 49) {
        const float4* kp = (const float4*)(know + (size_t)b * DIM * NN) + (size_t)(ty * 32) * 49 + tx;
        const float*  wp = w_s + ty * 32;
        #pragma unroll 8
        for (int dd = 0; dd < 32; ++dd) {
            const float4 kv = kp[(size_t)dd * 49];
            const float  wv = wp[dd];
            lg.x = fmaf(kv.x, wv, lg.x); lg.y = fmaf(kv.y, wv, lg.y);
            lg.z = fmaf(kv.z, wv, lg.z); lg.w = fmaf(kv.w, wv, lg.w);
            ks.x += kv.x; ks.y += kv.y; ks.z += kv.z; ks.w += kv.w;
        }
        part_lg[ty][tx] = lg;
        part_ks[ty][tx] = ks;
    }
    __syncthreads();

    float lgn = 0.f, ksn = 0.f;
    if (tid < NN) {
        const int ng = tid >> 2, j = tid & 3;
        #pragma unroll
        for (int t = 0; t < 16; ++t) {
            lgn += ((const float*)&part_lg[t][ng])[j];
            ksn += ((const float*)&part_ks[t][ng])[j];
        }
    }

    if (tid < 256) tmp[tid] = (tid < NN) ? lgn : -FLT_MAX;
    __syncthreads();
    if (tid < 64) {
        float m = fmaxf(fmaxf(tmp[tid], tmp[tid + 64]),
                        fmaxf(tmp[tid + 128], tmp[tid + 192]));
        #pragma unroll
        for (int o = 32; o; o >>= 1) m = fmaxf(m, __shfl_down(m, o));
        if (tid == 0) bc[0] = m;
    }
    __syncthreads();

    const float e = (tid < NN) ? __expf(lgn - bc[0]) : 0.f;
    if (tid < 256) tmp[tid] = e;
    __syncthreads();
    if (tid < 64) {
        float s = tmp[tid] + tmp[tid + 64] + tmp[tid + 128] + tmp[tid + 192];
        #pragma unroll
        for (int o = 32; o; o >>= 1) s += __shfl_down(s, o);
        if (tid == 0) bc[1] = s;
    }
    __syncthreads();

    if (tid < NN) out[(size_t)b * NN + tid] = e / bc[1] * ksn;
}

// ---------------------------------------------------------------------------
extern "C" void kernel_launch(void* const* d_in, const int* in_sizes, int n_in,
                              void* d_out, int out_size, void* d_ws, size_t ws_size,
                              hipStream_t stream) {
    const float* memory   = (const float*)d_in[0];
    const float* know     = (const float*)d_in[1];
    const float* control  = (const float*)d_in[2];
    const float* W_mem    = (const float*)d_in[3];
    const float* b_mem    = (const float*)d_in[4];
    const float* W_concat = (const float*)d_in[5];
    // d_in[6] = b_concat : uniform over n -> softmax-invariant, unused
    const float* W_attn   = (const float*)d_in[7];
    // d_in[8] = b_attn   : same, unused
    float* w_ws = (float*)d_ws;          // (BB, DIM) = 512 KB scratch
    float* outp = (float*)d_out;

    void* args[] = { (void*)&memory, (void*)&control, (void*)&W_mem,
                     (void*)&b_mem, (void*)&W_concat, (void*)&W_attn,
                     (void*)&know, (void*)&w_ws, (void*)&outp };
    hipError_t err = hipLaunchCooperativeKernel(
        (const void*)fused_kernel, dim3(BB), dim3(1024), args, 0, stream);

    if (err != hipSuccess) {
        // fallback: proven r11 f32 prep + r6 read (36.5 us path)
        prep_fallback<<<dim3(BB / 8, DIM / 32), dim3(512), 0, stream>>>(
            memory, control, W_mem, b_mem, W_concat, W_attn, w_ws);
        read_kernel<<<dim3(BB), dim3(64, 16), 0, stream>>>(know, w_ws, outp);
    }
}

// Round 19
// 30.114 us; speedup vs baseline: 3.9442x; 3.9442x over previous
//
#include <hip/hip_runtime.h>
#include <cfloat>

// Problem dims (fixed by reference)
#define BB   256   // batch
#define DIM  512
#define NN   196

typedef __attribute__((ext_vector_type(8))) short bf16x8;   // 8 bf16 (4 VGPRs)
typedef __attribute__((ext_vector_type(4))) float f32x4;    // MFMA acc

__device__ __forceinline__ ushort f2bf(float x) {          // RNE f32->bf16
    unsigned u = __float_as_uint(x);
    return (ushort)((u + 0x7FFFu + ((u >> 16) & 1u)) >> 16);
}

__device__ __forceinline__ bf16x8 pack8(float4 a, float4 b) {
    union { bf16x8 v; ushort u[8]; } r;
    r.u[0] = f2bf(a.x); r.u[1] = f2bf(a.y); r.u[2] = f2bf(a.z); r.u[3] = f2bf(a.w);
    r.u[4] = f2bf(b.x); r.u[5] = f2bf(b.y); r.u[6] = f2bf(b.z); r.u[7] = f2bf(b.w);
    return r.v;
}

// ---------------------------------------------------------------------------
// Kernel 1: prep_fused — w[b,i] = (mem[b,i]+b_mem[i])*v1[b,i] + v2[b,i]
// Single kernel replaces convert + prep_mfma (r16's fusion idea with r16's
// occupancy bug fixed: 8 waves/block, not 2).
// grid (BB/16, DIM/32) = (16,16) x 512 thr. Wave wv owns k-chunk
// [wv*64, wv*64+64); per wave: 2 i-subtiles x 2 k-steps x 3 MFMAs = 12.
// bf16 conversion in-flight: m/u -> LDS bf16 (W_attn fused); W_mem consumed
// NATIVELY row-major [k][i] (B-fragment is k-indexed; 8 strided f32/lane,
// coalesced per 16-lane group); W_concat rows contiguous (2 float4 -> pack).
// 8 k-partials reduced via 48 KB LDS arena (reduce reads conflict-free).
// Fragment maps (m89-verified): A lane l -> row=l&15, k=8*(l>>4)+j ;
// B lane l -> col=l&15, k same ; D lane l -> col=l&15, row=4*(l>>4)+reg.
// ---------------------------------------------------------------------------
__global__ __launch_bounds__(512) void prep_fused(
    const float* __restrict__ memory,    // (2,BB,DIM)
    const float* __restrict__ control,   // (2,BB,DIM)
    const float* __restrict__ W_mem,     // (DIM,DIM) [k][i]
    const float* __restrict__ b_mem,     // (DIM)
    const float* __restrict__ W_concat,  // (2*DIM,DIM) [c][j]
    const float* __restrict__ W_attn,    // (DIM,1)
    float* __restrict__ w_out)           // (BB, DIM)
{
    __shared__ __align__(16) unsigned char smem[49152];   // 48 KB union

    const int tid = threadIdx.x;     // 0..511
    const int b0  = blockIdx.x * 16;
    const int i0  = blockIdx.y * 32;

    ushort (*mus)[16][520] = (ushort (*)[16][520])smem;   // 33.3 KB

    const float* mem_in = memory  + (size_t)BB * DIM;     // memory[-1]
    const float* ctl_in = control + (size_t)BB * DIM;     // control[-1]

    // ---- stage m,u for 16 b rows -> bf16 LDS (4096 f4, 8/thread) ----
    // a = idx>>11 is uniform per p (p<4 -> m, p>=4 -> u): no divergence.
    #pragma unroll
    for (int p = 0; p < 8; ++p) {
        const int idx = p * 512 + tid;        // 0..4095
        const int a   = idx >> 11;            // 0 = m, 1 = u
        const int rb  = (idx >> 7) & 15;      // b row
        const int k4  = idx & 127;            // float4 index within row
        const float* src = a ? ctl_in : mem_in;
        float4 q = *(const float4*)&src[(size_t)(b0 + rb) * DIM + k4 * 4];
        if (a) {
            const float4 wa = ((const float4*)W_attn)[k4];
            q.x *= wa.x; q.y *= wa.y; q.z *= wa.z; q.w *= wa.w;
        }
        uint2 o;
        o.x = (unsigned)f2bf(q.x) | ((unsigned)f2bf(q.y) << 16);
        o.y = (unsigned)f2bf(q.z) | ((unsigned)f2bf(q.w) << 16);
        *(uint2*)&mus[a][rb][k4 * 4] = o;
    }
    __syncthreads();

    const int wv = tid >> 6;         // 0..7 : k-chunk owner
    const int l  = tid & 63;
    const int fr = l & 15;           // A row (b) / B col (i) / D col (i)
    const int fk = (l >> 4) * 8;     // k offset within 32-step

    f32x4 accM[2] = {{0.f,0.f,0.f,0.f}, {0.f,0.f,0.f,0.f}};
    f32x4 acc1[2] = {{0.f,0.f,0.f,0.f}, {0.f,0.f,0.f,0.f}};
    f32x4 acc2[2] = {{0.f,0.f,0.f,0.f}, {0.f,0.f,0.f,0.f}};

    #pragma unroll
    for (int s = 0; s < 2; ++s) {
        const int ib = i0 + s * 16 + fr;
        const float* wmp = W_mem + ib;
        const float* c1p = W_concat + (size_t)ib * DIM;
        const float* c2p = W_concat + (size_t)(DIM + ib) * DIM;
        #pragma unroll
        for (int ts = 0; ts < 2; ++ts) {
            const int k = wv * 64 + ts * 32 + fk;
            const bf16x8 am = *(const bf16x8*)&mus[0][fr][k];
            const bf16x8 au = *(const bf16x8*)&mus[1][fr][k];
            // W_mem native [k][i]: 8 strided f32, coalesced per 16-lane group
            float wmv[8];
            #pragma unroll
            for (int j = 0; j < 8; ++j) wmv[j] = wmp[(size_t)(k + j) * DIM];
            union { bf16x8 v; ushort u[8]; } bm;
            #pragma unroll
            for (int j = 0; j < 8; ++j) bm.u[j] = f2bf(wmv[j]);
            const bf16x8 b1 = pack8(*(const float4*)&c1p[k],
                                    *(const float4*)&c1p[k + 4]);
            const bf16x8 b2 = pack8(*(const float4*)&c2p[k],
                                    *(const float4*)&c2p[k + 4]);
            accM[s] = __builtin_amdgcn_mfma_f32_16x16x32_bf16(am, bm.v, accM[s], 0, 0, 0);
            acc1[s] = __builtin_amdgcn_mfma_f32_16x16x32_bf16(au, b1,   acc1[s], 0, 0, 0);
            acc2[s] = __builtin_amdgcn_mfma_f32_16x16x32_bf16(au, b2,   acc2[s], 0, 0, 0);
        }
    }

    // ---- reduce 8 k-partials via LDS: P[acc][wv][b_local*32 + i_local] ----
    __syncthreads();                 // all waves done reading mus
    float* P = (float*)smem;         // 3 * 8 * 512 floats = 48 KB exactly
    const int rb0 = (l >> 4) * 4;
    #pragma unroll
    for (int s = 0; s < 2; ++s) {
        #pragma unroll
        for (int r = 0; r < 4; ++r) {
            const int idx = (rb0 + r) * 32 + s * 16 + fr;   // ~4-way write conflict, tiny
            P[(0 * 8 + wv) * 512 + idx] = accM[s][r];
            P[(1 * 8 + wv) * 512 + idx] = acc1[s][r];
            P[(2 * 8 + wv) * 512 + idx] = acc2[s][r];
        }
    }
    __syncthreads();
    {
        float sm = 0.f, v1 = 0.f, v2 = 0.f;
        #pragma unroll
        for (int c = 0; c < 8; ++c) {      // consecutive tid -> conflict-free
            sm += P[(0 * 8 + c) * 512 + tid];
            v1 += P[(1 * 8 + c) * 512 + tid];
            v2 += P[(2 * 8 + c) * 512 + tid];
        }
        const int bl = tid >> 5, il = tid & 31;
        const int i  = i0 + il;
        w_out[(size_t)(b0 + bl) * DIM + i] = (sm + b_mem[i]) * v1 + v2;
    }
}

// ---------------------------------------------------------------------------
// Kernel 2: per-b streaming pass over know (float4, 16 waves/block).
// (byte-identical to round 6 — best proven read)
// ---------------------------------------------------------------------------
__global__ __launch_bounds__(1024) void read_kernel(
    const float* __restrict__ know,  // (BB, DIM, NN)
    const float* __restrict__ w,     // (BB, DIM)
    float* __restrict__ out)         // (BB, NN)
{
    __shared__ float  w_s[DIM];
    __shared__ float4 part_lg[16][50];
    __shared__ float4 part_ks[16][50];
    __shared__ float  tmp[256];
    __shared__ float  bc[2];

    const int tx  = threadIdx.x;       // 0..63 (lane)
    const int ty  = threadIdx.y;       // 0..15 (wave)
    const int tid = ty * 64 + tx;
    const int b   = blockIdx.x;

    if (tid < DIM) w_s[tid] = w[(size_t)b * DIM + tid];
    __syncthreads();

    float4 lg = make_float4(0.f, 0.f, 0.f, 0.f);
    float4 ks = make_float4(0.f, 0.f, 0.f, 0.f);
    if (tx < 49) {
        const float4* kp = (const float4*)(know + (size_t)b * DIM * NN) + (size_t)(ty * 32) * 49 + tx;
        const float*  wp = w_s + ty * 32;
        #pragma unroll 8
        for (int dd = 0; dd < 32; ++dd) {
            const float4 kv = kp[(size_t)dd * 49];
            const float  wv = wp[dd];
            lg.x = fmaf(kv.x, wv, lg.x); lg.y = fmaf(kv.y, wv, lg.y);
            lg.z = fmaf(kv.z, wv, lg.z); lg.w = fmaf(kv.w, wv, lg.w);
            ks.x += kv.x; ks.y += kv.y; ks.z += kv.z; ks.w += kv.w;
        }
        part_lg[ty][tx] = lg;
        part_ks[ty][tx] = ks;
    }
    __syncthreads();

    float lgn = 0.f, ksn = 0.f;
    if (tid < NN) {
        const int ng = tid >> 2, j = tid & 3;
        #pragma unroll
        for (int t = 0; t < 16; ++t) {
            lgn += ((const float*)&part_lg[t][ng])[j];
            ksn += ((const float*)&part_ks[t][ng])[j];
        }
    }

    if (tid < 256) tmp[tid] = (tid < NN) ? lgn : -FLT_MAX;
    __syncthreads();
    if (tid < 64) {
        float m = fmaxf(fmaxf(tmp[tid], tmp[tid + 64]),
                        fmaxf(tmp[tid + 128], tmp[tid + 192]));
        #pragma unroll
        for (int o = 32; o; o >>= 1) m = fmaxf(m, __shfl_down(m, o));
        if (tid == 0) bc[0] = m;
    }
    __syncthreads();

    const float e = (tid < NN) ? __expf(lgn - bc[0]) : 0.f;
    if (tid < 256) tmp[tid] = e;
    __syncthreads();
    if (tid < 64) {
        float s = tmp[tid] + tmp[tid + 64] + tmp[tid + 128] + tmp[tid + 192];
        #pragma unroll
        for (int o = 32; o; o >>= 1) s += __shfl_down(s, o);
        if (tid == 0) bc[1] = s;
    }
    __syncthreads();

    if (tid < NN) out[(size_t)b * NN + tid] = e / bc[1] * ksn;
}

// ---------------------------------------------------------------------------
extern "C" void kernel_launch(void* const* d_in, const int* in_sizes, int n_in,
                              void* d_out, int out_size, void* d_ws, size_t ws_size,
                              hipStream_t stream) {
    const float* memory   = (const float*)d_in[0];
    const float* know     = (const float*)d_in[1];
    const float* control  = (const float*)d_in[2];
    const float* W_mem    = (const float*)d_in[3];
    const float* b_mem    = (const float*)d_in[4];
    const float* W_concat = (const float*)d_in[5];
    // d_in[6] = b_concat : uniform over n -> softmax-invariant, unused
    const float* W_attn   = (const float*)d_in[7];
    // d_in[8] = b_attn   : same, unused
    float* w_ws = (float*)d_ws;          // (BB, DIM) = 512 KB scratch
    float* outp = (float*)d_out;         // (BB, NN) f32

    prep_fused<<<dim3(BB / 16, DIM / 32), dim3(512), 0, stream>>>(
        memory, control, W_mem, b_mem, W_concat, W_attn, w_ws);
    read_kernel<<<dim3(BB), dim3(64, 16), 0, stream>>>(know, w_ws, outp);
}

// Round 20
// 29.936 us; speedup vs baseline: 3.9678x; 1.0060x over previous
//
#include <hip/hip_runtime.h>
#include <cfloat>

// Problem dims (fixed by reference)
#define BB   256   // batch
#define DIM  512
#define NN   196

typedef __attribute__((ext_vector_type(8))) short bf16x8;   // 8 bf16 (4 VGPRs)
typedef __attribute__((ext_vector_type(4))) float f32x4;    // MFMA acc

__device__ __forceinline__ ushort f2bf(float x) {          // RNE f32->bf16
    unsigned u = __float_as_uint(x);
    return (ushort)((u + 0x7FFFu + ((u >> 16) & 1u)) >> 16);
}

__device__ __forceinline__ bf16x8 pack8(float4 a, float4 b) {
    union { bf16x8 v; ushort u[8]; } r;
    r.u[0] = f2bf(a.x); r.u[1] = f2bf(a.y); r.u[2] = f2bf(a.z); r.u[3] = f2bf(a.w);
    r.u[4] = f2bf(b.x); r.u[5] = f2bf(b.y); r.u[6] = f2bf(b.z); r.u[7] = f2bf(b.w);
    return r.v;
}

// ---------------------------------------------------------------------------
// Kernel 1: prep_fused v2 — w[b,i] = (mem[b,i]+b_mem[i])*v1[b,i] + v2[b,i]
// r19 structure with i-tile halved for occupancy: grid (BB/16, DIM/16) =
// (16,32) = 512 blocks x 512 thr -> 2-4 blocks/CU (LDS 33.3 KB), so the
// staging barrier + strided-load chains of one block hide under another.
// Wave wv (0..7) owns k-chunk [wv*64, +64); one 16-i subtile; 2 k-steps
// x 3 MFMA = 6 MFMA/wave. bf16 conversion in-flight (r19-proven):
// m/u -> LDS bf16 (W_attn fused); W_mem consumed NATIVELY [k][i] (B-frag
// is k-indexed; 8 strided f32/lane, coalesced per 16-lane group);
// W_concat rows contiguous (2 float4 -> pack). 8 k-partials via LDS arena.
// Fragment maps (m89-verified): A lane l -> row=l&15, k=8*(l>>4)+j ;
// B lane l -> col=l&15, k same ; D lane l -> col=l&15, row=4*(l>>4)+reg.
// ---------------------------------------------------------------------------
__global__ __launch_bounds__(512) void prep_fused(
    const float* __restrict__ memory,    // (2,BB,DIM)
    const float* __restrict__ control,   // (2,BB,DIM)
    const float* __restrict__ W_mem,     // (DIM,DIM) [k][i]
    const float* __restrict__ b_mem,     // (DIM)
    const float* __restrict__ W_concat,  // (2*DIM,DIM) [c][j]
    const float* __restrict__ W_attn,    // (DIM,1)
    float* __restrict__ w_out)           // (BB, DIM)
{
    // union: mus[2][16][520] ushort = 33,280 B ; reduce arena 24,576 B
    __shared__ __align__(16) unsigned char smem[33280];

    const int tid = threadIdx.x;     // 0..511
    const int b0  = blockIdx.x * 16;
    const int i0  = blockIdx.y * 16;

    ushort (*mus)[16][520] = (ushort (*)[16][520])smem;

    const float* mem_in = memory  + (size_t)BB * DIM;     // memory[-1]
    const float* ctl_in = control + (size_t)BB * DIM;     // control[-1]

    // ---- stage m,u for 16 b rows -> bf16 LDS (4096 f4, 8/thread) ----
    // a = idx>>11 is uniform per p (p<4 -> m, p>=4 -> u): no divergence.
    #pragma unroll
    for (int p = 0; p < 8; ++p) {
        const int idx = p * 512 + tid;        // 0..4095
        const int a   = idx >> 11;            // 0 = m, 1 = u
        const int rb  = (idx >> 7) & 15;      // b row
        const int k4  = idx & 127;            // float4 index within row
        const float* src = a ? ctl_in : mem_in;
        float4 q = *(const float4*)&src[(size_t)(b0 + rb) * DIM + k4 * 4];
        if (a) {
            const float4 wa = ((const float4*)W_attn)[k4];
            q.x *= wa.x; q.y *= wa.y; q.z *= wa.z; q.w *= wa.w;
        }
        uint2 o;
        o.x = (unsigned)f2bf(q.x) | ((unsigned)f2bf(q.y) << 16);
        o.y = (unsigned)f2bf(q.z) | ((unsigned)f2bf(q.w) << 16);
        *(uint2*)&mus[a][rb][k4 * 4] = o;
    }
    __syncthreads();

    const int wv = tid >> 6;         // 0..7 : k-chunk owner
    const int l  = tid & 63;
    const int fr = l & 15;           // A row (b) / B col (i) / D col (i)
    const int fk = (l >> 4) * 8;     // k offset within 32-step

    f32x4 accM = {0.f,0.f,0.f,0.f};
    f32x4 acc1 = {0.f,0.f,0.f,0.f};
    f32x4 acc2 = {0.f,0.f,0.f,0.f};

    const int ib = i0 + fr;          // this lane's i
    const float* wmp = W_mem + ib;
    const float* c1p = W_concat + (size_t)ib * DIM;
    const float* c2p = W_concat + (size_t)(DIM + ib) * DIM;

    #pragma unroll
    for (int ts = 0; ts < 2; ++ts) {
        const int k = wv * 64 + ts * 32 + fk;
        const bf16x8 am = *(const bf16x8*)&mus[0][fr][k];
        const bf16x8 au = *(const bf16x8*)&mus[1][fr][k];
        // W_mem native [k][i]: 8 strided f32, coalesced per 16-lane group
        float wmv[8];
        #pragma unroll
        for (int j = 0; j < 8; ++j) wmv[j] = wmp[(size_t)(k + j) * DIM];
        union { bf16x8 v; ushort u[8]; } bm;
        #pragma unroll
        for (int j = 0; j < 8; ++j) bm.u[j] = f2bf(wmv[j]);
        const bf16x8 b1 = pack8(*(const float4*)&c1p[k],
                                *(const float4*)&c1p[k + 4]);
        const bf16x8 b2 = pack8(*(const float4*)&c2p[k],
                                *(const float4*)&c2p[k + 4]);
        accM = __builtin_amdgcn_mfma_f32_16x16x32_bf16(am, bm.v, accM, 0, 0, 0);
        acc1 = __builtin_amdgcn_mfma_f32_16x16x32_bf16(au, b1,   acc1, 0, 0, 0);
        acc2 = __builtin_amdgcn_mfma_f32_16x16x32_bf16(au, b2,   acc2, 0, 0, 0);
    }

    // ---- reduce 8 k-partials via LDS arena: P[acc][wv][b_local*16 + i_local]
    __syncthreads();                 // all waves done reading mus
    float* P = (float*)smem;         // 3 * 8 * 256 floats = 24,576 B
    const int rb0 = (l >> 4) * 4;
    #pragma unroll
    for (int r = 0; r < 4; ++r) {
        const int idx = (rb0 + r) * 16 + fr;
        P[(0 * 8 + wv) * 256 + idx] = accM[r];
        P[(1 * 8 + wv) * 256 + idx] = acc1[r];
        P[(2 * 8 + wv) * 256 + idx] = acc2[r];
    }
    __syncthreads();
    if (tid < 256) {
        float sm = 0.f, v1 = 0.f, v2 = 0.f;
        #pragma unroll
        for (int c = 0; c < 8; ++c) {      // consecutive tid -> conflict-free
            sm += P[(0 * 8 + c) * 256 + tid];
            v1 += P[(1 * 8 + c) * 256 + tid];
            v2 += P[(2 * 8 + c) * 256 + tid];
        }
        const int bl = tid >> 4, il = tid & 15;
        const int i  = i0 + il;
        w_out[(size_t)(b0 + bl) * DIM + i] = (sm + b_mem[i]) * v1 + v2;
    }
}

// ---------------------------------------------------------------------------
// Kernel 2: per-b streaming pass over know (float4, 16 waves/block).
// (byte-identical to round 6 — best proven read)
// ---------------------------------------------------------------------------
__global__ __launch_bounds__(1024) void read_kernel(
    const float* __restrict__ know,  // (BB, DIM, NN)
    const float* __restrict__ w,     // (BB, DIM)
    float* __restrict__ out)         // (BB, NN)
{
    __shared__ float  w_s[DIM];
    __shared__ float4 part_lg[16][50];
    __shared__ float4 part_ks[16][50];
    __shared__ float  tmp[256];
    __shared__ float  bc[2];

    const int tx  = threadIdx.x;       // 0..63 (lane)
    const int ty  = threadIdx.y;       // 0..15 (wave)
    const int tid = ty * 64 + tx;
    const int b   = blockIdx.x;

    if (tid < DIM) w_s[tid] = w[(size_t)b * DIM + tid];
    __syncthreads();

    float4 lg = make_float4(0.f, 0.f, 0.f, 0.f);
    float4 ks = make_float4(0.f, 0.f, 0.f, 0.f);
    if (tx < 49) {
        const float4* kp = (const float4*)(know + (size_t)b * DIM * NN) + (size_t)(ty * 32) * 49 + tx;
        const float*  wp = w_s + ty * 32;
        #pragma unroll 8
        for (int dd = 0; dd < 32; ++dd) {
            const float4 kv = kp[(size_t)dd * 49];
            const float  wv = wp[dd];
            lg.x = fmaf(kv.x, wv, lg.x); lg.y = fmaf(kv.y, wv, lg.y);
            lg.z = fmaf(kv.z, wv, lg.z); lg.w = fmaf(kv.w, wv, lg.w);
            ks.x += kv.x; ks.y += kv.y; ks.z += kv.z; ks.w += kv.w;
        }
        part_lg[ty][tx] = lg;
        part_ks[ty][tx] = ks;
    }
    __syncthreads();

    float lgn = 0.f, ksn = 0.f;
    if (tid < NN) {
        const int ng = tid >> 2, j = tid & 3;
        #pragma unroll
        for (int t = 0; t < 16; ++t) {
            lgn += ((const float*)&part_lg[t][ng])[j];
            ksn += ((const float*)&part_ks[t][ng])[j];
        }
    }

    if (tid < 256) tmp[tid] = (tid < NN) ? lgn : -FLT_MAX;
    __syncthreads();
    if (tid < 64) {
        float m = fmaxf(fmaxf(tmp[tid], tmp[tid + 64]),
                        fmaxf(tmp[tid + 128], tmp[tid + 192]));
        #pragma unroll
        for (int o = 32; o; o >>= 1) m = fmaxf(m, __shfl_down(m, o));
        if (tid == 0) bc[0] = m;
    }
    __syncthreads();

    const float e = (tid < NN) ? __expf(lgn - bc[0]) : 0.f;
    if (tid < 256) tmp[tid] = e;
    __syncthreads();
    if (tid < 64) {
        float s = tmp[tid] + tmp[tid + 64] + tmp[tid + 128] + tmp[tid + 192];
        #pragma unroll
        for (int o = 32; o; o >>= 1) s += __shfl_down(s, o);
        if (tid == 0) bc[1] = s;
    }
    __syncthreads();

    if (tid < NN) out[(size_t)b * NN + tid] = e / bc[1] * ksn;
}

// ---------------------------------------------------------------------------
extern "C" void kernel_launch(void* const* d_in, const int* in_sizes, int n_in,
                              void* d_out, int out_size, void* d_ws, size_t ws_size,
                              hipStream_t stream) {
    const float* memory   = (const float*)d_in[0];
    const float* know     = (const float*)d_in[1];
    const float* control  = (const float*)d_in[2];
    const float* W_mem    = (const float*)d_in[3];
    const float* b_mem    = (const float*)d_in[4];
    const float* W_concat = (const float*)d_in[5];
    // d_in[6] = b_concat : uniform over n -> softmax-invariant, unused
    const float* W_attn   = (const float*)d_in[7];
    // d_in[8] = b_attn   : same, unused
    float* w_ws = (float*)d_ws;          // (BB, DIM) = 512 KB scratch
    float* outp = (float*)d_out;         // (BB, NN) f32

    prep_fused<<<dim3(BB / 16, DIM / 16), dim3(512), 0, stream>>>(
        memory, control, W_mem, b_mem, W_concat, W_attn, w_ws);
    read_kernel<<<dim3(BB), dim3(64, 16), 0, stream>>>(know, w_ws, outp);
}